// Round 4
// baseline (377.936 us; speedup 1.0000x reference)
//
#include <hip/hip_runtime.h>
#include <math.h>

#define KDIM 32
#define MDIM 256
#define NDIM 2048
#define NNLS_TOL 1e-6f

// ---------------- helpers ----------------
__device__ __forceinline__ float lane_bcast(float x, int lane) {
  // compile-time lane -> v_readlane_b32 (SGPR broadcast), no LDS, no bpermute
  return __int_as_float(__builtin_amdgcn_readlane(__float_as_int(x), lane));
}
__device__ __forceinline__ float fast_rcp(float x) {
  float r;
  asm("v_rcp_f32 %0, %1" : "=v"(r) : "v"(x));
  r = r * (2.0f - x * r);  // one Newton step; protects the 3e-3 margin
  return r;
}

// ---------------- AtA = A^T A (32x32) + packed LU factor (shared by all cols) --
__global__ __launch_bounds__(1024) void ata_kernel(const float* __restrict__ A,
                                                   float* __restrict__ AtA,
                                                   float* __restrict__ LU) {
  __shared__ float As[MDIM * KDIM];    // 32 KB
  __shared__ float AtAs[KDIM * KDIM];  // 4 KB
  const int t = threadIdx.x;
  for (int i = t; i < MDIM * KDIM; i += 1024) As[i] = A[i];
  __syncthreads();
  {
    const int i = t >> 5, j = t & 31;  // one output element per thread
    float acc = 0.f;
#pragma unroll 8
    for (int m = 0; m < MDIM; ++m) acc = fmaf(As[m * KDIM + i], As[m * KDIM + j], acc);
    AtAs[i * KDIM + j] = acc;
    AtA[i * KDIM + j] = acc;
  }
  __syncthreads();
  // one wave: dense register GE; L multipliers below diag, U on/above
  if (t < 64) {
    const int r = t & 31;
    float m[KDIM];
#pragma unroll
    for (int c = 0; c < KDIM; ++c) m[c] = AtAs[r * KDIM + c];
#pragma unroll
    for (int j = 0; j < KDIM - 1; ++j) {
      const float inv = fast_rcp(lane_bcast(m[j], j));
      const float f = (r > j) ? m[j] * inv : 0.f;
#pragma unroll
      for (int c = j + 1; c < KDIM; ++c) m[c] = fmaf(-f, lane_bcast(m[c], j), m[c]);
      if (r > j) m[j] = f;  // pack multiplier
    }
    if (t < 32) {
#pragma unroll
      for (int c = 0; c < KDIM; ++c) LU[r * KDIM + c] = m[c];
    }
  }
}

// ---------------- AtXt[n][k] = (A^T X)^T  (2048x32) ----------------
// 32 blocks x 256 threads. Block owns 64 columns; wave w owns m-chunk
// [64w, 64w+64). A-operands are wave-uniform (readfirstlane -> scalar loads);
// X loads coalesced (64 consecutive floats per wave). One LDS reduce + one sync.
__global__ __launch_bounds__(256) void atx_kernel(const float* __restrict__ A,
                                                  const float* __restrict__ X,
                                                  float* __restrict__ AtXt) {
  __shared__ float red[4][KDIM][65];  // padded: reduce reads spread banks
  const int t = threadIdx.x;
  const int nl = t & 63;
  const int w = t >> 6;  // wave id == m-chunk
  const int n = blockIdx.x * 64 + nl;

  float acc[KDIM];
#pragma unroll
  for (int k = 0; k < KDIM; ++k) acc[k] = 0.f;
  const int m0 = w * 64;
#pragma unroll 4
  for (int mm = 0; mm < 64; ++mm) {
    const int m = __builtin_amdgcn_readfirstlane(m0 + mm);  // wave-uniform
    const float x = X[m * NDIM + n];  // coalesced 256B/wave
#pragma unroll
    for (int k = 0; k < KDIM; ++k) acc[k] = fmaf(A[m * KDIM + k], x, acc[k]);
  }
#pragma unroll
  for (int k = 0; k < KDIM; ++k) red[w][k][nl] = acc[k];
  __syncthreads();
  // final reduce over 4 m-chunks; fully coalesced float4 stores (8 el/thread)
#pragma unroll
  for (int i2 = 0; i2 < 2; ++i2) {
    float v[4];
#pragma unroll
    for (int q = 0; q < 4; ++q) {
      const int f = t * 8 + i2 * 4 + q;  // block-local flat = n_local*32 + k
      const int kk = f & 31, nn = f >> 5;
      float s = 0.f;
#pragma unroll
      for (int g = 0; g < 4; ++g) s += red[g][kk][nn];
      v[q] = s;
    }
    float4 o = {v[0], v[1], v[2], v[3]};
    reinterpret_cast<float4*>(AtXt + blockIdx.x * 64 * KDIM)[t * 2 + i2] = o;
  }
}

// ---------------- per-column NNLS: block principal pivoting, all-register ------
// Lane l owns row r=l&31; hi half mirrors lo so all branches are wave-uniform.
// KKT fixed point is unique (AtA SPD) => matches the reference's active-set
// solution within solver tolerance regardless of pivot order.
__global__ __launch_bounds__(64) void nnls_kernel(const float* __restrict__ AtA_g,
                                                  const float* __restrict__ LU_g,
                                                  const float* __restrict__ AtXt,
                                                  float* __restrict__ S) {
  const int l = threadIdx.x;
  const int r = l & 31;
  const int n = blockIdx.x;

  float ata[KDIM], lu[KDIM];
#pragma unroll
  for (int q = 0; q < KDIM / 4; ++q) {
    const float4 v = reinterpret_cast<const float4*>(AtA_g + r * KDIM)[q];
    ata[4 * q + 0] = v.x; ata[4 * q + 1] = v.y; ata[4 * q + 2] = v.z; ata[4 * q + 3] = v.w;
    const float4 u = reinterpret_cast<const float4*>(LU_g + r * KDIM)[q];
    lu[4 * q + 0] = u.x; lu[4 * q + 1] = u.y; lu[4 * q + 2] = u.z; lu[4 * q + 3] = u.w;
  }
  const float atb = AtXt[n * KDIM + r];  // coalesced 128B per block

  // masked solve: (AtA o PP^T + diag(1-P)) z = P o Atb, registers + readlane only
  auto solve = [&](unsigned int Pm) -> float {
    const bool actl = (Pm >> r) & 1u;
    float m[KDIM];
#pragma unroll
    for (int c = 0; c < KDIM; ++c) {
      const bool actc = (Pm >> c) & 1u;
      m[c] = (actl && actc) ? ata[c] : ((r == c) ? 1.f : 0.f);
    }
    float rhs = actl ? atb : 0.f;
#pragma unroll
    for (int j = 0; j < KDIM - 1; ++j) {
      if ((Pm >> j) & 1u) {
        const float inv = fast_rcp(lane_bcast(m[j], j));
        const float f = (r > j) ? m[j] * inv : 0.f;
#pragma unroll
        for (int c = j + 1; c < KDIM; ++c) m[c] = fmaf(-f, lane_bcast(m[c], j), m[c]);
        rhs = fmaf(-f, lane_bcast(rhs, j), rhs);
      }
    }
    float zz = 0.f;
#pragma unroll
    for (int j = KDIM - 1; j >= 0; --j) {
      if ((Pm >> j) & 1u) {
        const float xj = lane_bcast(rhs, j) * fast_rcp(lane_bcast(m[j], j));
        if (r == j) zz = xj;
        if (r < j) rhs = fmaf(-m[j], xj, rhs);
      }
    }
    return zz;
  };

  unsigned int P;
  float z;
  {
    const unsigned long long b0 = __ballot(atb > NNLS_TOL);
    const unsigned int P0 = (unsigned int)(b0 & 0xffffffffull);
    if (P0 == 0xffffffffu) {
      // shared-LU fast path: forward/back substitution only (~260 VALU)
      P = P0;
      float rhs = atb;
#pragma unroll
      for (int j = 0; j < KDIM - 1; ++j) {
        const float fj = (r > j) ? lu[j] : 0.f;
        rhs = fmaf(-fj, lane_bcast(rhs, j), rhs);
      }
      z = 0.f;
#pragma unroll
      for (int j = KDIM - 1; j >= 0; --j) {
        const float xj = lane_bcast(rhs, j) * fast_rcp(lane_bcast(lu[j], j));
        if (r == j) z = xj;
        const float uj = (r < j) ? lu[j] : 0.f;
        rhs = fmaf(-uj, xj, rhs);
      }
    } else {
      // rare/robustness path: let the loop's block step add P0 and solve
      P = 0u;
      z = 0.f;
    }
  }

  // block principal pivoting with Murty least-index safeguard
  int ninf_best = 1000, budget = 3;
  for (int it = 0; it < 100; ++it) {
    const bool act = (P >> r) & 1u;
    const float zm = act ? z : 0.f;
    float w = atb;
#pragma unroll
    for (int c = 0; c < KDIM; ++c) w = fmaf(-ata[c], lane_bcast(zm, c), w);
    const unsigned long long bb = __ballot(act && (z <= NNLS_TOL));
    const unsigned long long vb = __ballot((!act) && (w > NNLS_TOL));
    const unsigned int bad = (unsigned int)(bb & 0xffffffffull);
    const unsigned int viol = (unsigned int)(vb & 0xffffffffull);
    const unsigned int u = bad | viol;
    if (u == 0u) break;  // KKT satisfied (uniform)
    const int ninf = __popc(u);
    bool useblock;
    if (ninf < ninf_best) { ninf_best = ninf; budget = 3; useblock = true; }
    else if (budget > 0) { --budget; useblock = true; }
    else { useblock = false; }
    if (useblock) {
      P = (P & ~bad) | viol;
    } else {
      const int j = __ffs(u) - 1;  // Murty: least-index single flip (finite for SPD)
      P ^= (1u << j);
    }
    z = solve(P);
  }

  if (l < KDIM) S[r * NDIM + n] = ((P >> r) & 1u) ? z : 0.f;
}

extern "C" void kernel_launch(void* const* d_in, const int* in_sizes, int n_in,
                              void* d_out, int out_size, void* d_ws, size_t ws_size,
                              hipStream_t stream) {
  const float* X = (const float*)d_in[0];  // [256, 2048]
  const float* A = (const float*)d_in[1];  // [256, 32]
  float* S = (float*)d_out;                // [32, 2048]
  float* AtA = (float*)d_ws;               // 1024 floats
  float* LU = AtA + KDIM * KDIM;           // 1024 floats
  float* AtXt = LU + KDIM * KDIM;          // 65536 floats, [n][k]

  ata_kernel<<<1, 1024, 0, stream>>>(A, AtA, LU);
  atx_kernel<<<NDIM / 64, 256, 0, stream>>>(A, X, AtXt);
  nnls_kernel<<<NDIM, 64, 0, stream>>>(AtA, LU, AtXt, S);
}

// Round 5
// 48.762 us; speedup vs baseline: 7.7506x; 7.7506x over previous
//
#include <hip/hip_runtime.h>
#include <math.h>

#define KDIM 32
#define MDIM 256
#define NDIM 2048
#define Z_TOL 1e-6f   // removal threshold (reference semantics)
#define W_TOL 1e-3f   // re-add threshold (hysteresis: kills z/w deadband cycling,
                      // since w_j = d_j*z_j with d_j <= max diag(AtA) ~ 330 < 1000)

// ---------------- helpers ----------------
__device__ __forceinline__ float lane_bcast(float x, int lane) {
  return __int_as_float(__builtin_amdgcn_readlane(__float_as_int(x), lane));
}
__device__ __forceinline__ float fast_rcp(float x) {
  float r;
  asm("v_rcp_f32 %0, %1" : "=v"(r) : "v"(x));
  r = r * (2.0f - x * r);  // one Newton step; protects the 3e-3 margin
  return r;
}

// ---------------- AtA = A^T A (32x32) + packed LU factor (shared by all cols) --
__global__ __launch_bounds__(1024) void ata_kernel(const float* __restrict__ A,
                                                   float* __restrict__ AtA,
                                                   float* __restrict__ LU) {
  __shared__ float As[MDIM * KDIM];    // 32 KB
  __shared__ float AtAs[KDIM * KDIM];  // 4 KB
  const int t = threadIdx.x;
  for (int i = t; i < MDIM * KDIM; i += 1024) As[i] = A[i];
  __syncthreads();
  {
    const int i = t >> 5, j = t & 31;  // one output element per thread
    float acc = 0.f;
#pragma unroll 8
    for (int m = 0; m < MDIM; ++m) acc = fmaf(As[m * KDIM + i], As[m * KDIM + j], acc);
    AtAs[i * KDIM + j] = acc;
    AtA[i * KDIM + j] = acc;
  }
  __syncthreads();
  // one wave: dense register GE; L multipliers below diag, U on/above
  if (t < 64) {
    const int r = t & 31;
    float m[KDIM];
#pragma unroll
    for (int c = 0; c < KDIM; ++c) m[c] = AtAs[r * KDIM + c];
#pragma unroll
    for (int j = 0; j < KDIM - 1; ++j) {
      const float inv = fast_rcp(lane_bcast(m[j], j));
      const float f = (r > j) ? m[j] * inv : 0.f;
#pragma unroll
      for (int c = j + 1; c < KDIM; ++c) m[c] = fmaf(-f, lane_bcast(m[c], j), m[c]);
      if (r > j) m[j] = f;  // pack multiplier
    }
    if (t < 32) {
#pragma unroll
      for (int c = 0; c < KDIM; ++c) LU[r * KDIM + c] = m[c];
    }
  }
}

// ---------------- per-column NNLS (fused Atb), one wave per column -------------
// Lane l owns row r=l&31; hi half mirrors lo so all branches are wave-uniform.
// Atb is computed in-wave: lane l accumulates 4 m-rows (m = q*64+l), then a
// lane-transposing butterfly delivers Atb[r] to lane r (hi half mirrored by the
// off=32 pre-step). Solver: block principal pivoting + Murty least-index
// safeguard, all-register GE solves with readlane broadcasts. No LDS.
__global__ __launch_bounds__(64, 2) void nnls_kernel(const float* __restrict__ A,
                                                     const float* __restrict__ AtA_g,
                                                     const float* __restrict__ LU_g,
                                                     const float* __restrict__ X,
                                                     float* __restrict__ S) {
  const int l = threadIdx.x;
  const int r = l & 31;
  const int n = blockIdx.x;

  // ---- phase 1: Atb = A^T X[:, n] ----
  float x4[4];
#pragma unroll
  for (int q = 0; q < 4; ++q) x4[q] = X[(q * 64 + l) * NDIM + n];
  float cur[KDIM];
#pragma unroll
  for (int k = 0; k < KDIM; ++k) cur[k] = 0.f;
#pragma unroll
  for (int q = 0; q < 4; ++q) {
    const int m = q * 64 + l;
#pragma unroll
    for (int qq = 0; qq < 8; ++qq) {
      const float4 a4 = reinterpret_cast<const float4*>(A + m * KDIM)[qq];
      cur[4 * qq + 0] = fmaf(a4.x, x4[q], cur[4 * qq + 0]);
      cur[4 * qq + 1] = fmaf(a4.y, x4[q], cur[4 * qq + 1]);
      cur[4 * qq + 2] = fmaf(a4.z, x4[q], cur[4 * qq + 2]);
      cur[4 * qq + 3] = fmaf(a4.w, x4[q], cur[4 * qq + 3]);
    }
  }
  // butterfly: sum over lanes, element k -> lane k (and lane k+32 mirrored)
#pragma unroll
  for (int k = 0; k < KDIM; ++k) cur[k] += __shfl_xor(cur[k], 32);
#pragma unroll
  for (int o = 16; o >= 1; o >>= 1) {
#pragma unroll
    for (int i = 0; i < o; ++i) {
      const bool hi = (l & o) != 0;
      const float a = cur[i], b = cur[i + o];
      const float mine = hi ? b : a;
      const float send = hi ? a : b;
      cur[i] = mine + __shfl_xor(send, o);
    }
  }
  const float atb = cur[0];  // = Atb[r], mirrored in hi half

  // ---- phase 2: load shared AtA row + LU row ----
  float ata[KDIM], lu[KDIM];
#pragma unroll
  for (int q = 0; q < KDIM / 4; ++q) {
    const float4 v = reinterpret_cast<const float4*>(AtA_g + r * KDIM)[q];
    ata[4 * q + 0] = v.x; ata[4 * q + 1] = v.y; ata[4 * q + 2] = v.z; ata[4 * q + 3] = v.w;
    const float4 u = reinterpret_cast<const float4*>(LU_g + r * KDIM)[q];
    lu[4 * q + 0] = u.x; lu[4 * q + 1] = u.y; lu[4 * q + 2] = u.z; lu[4 * q + 3] = u.w;
  }

  // masked solve: (AtA o PP^T + diag(1-P)) z = P o Atb, registers + readlane only
  auto solve = [&](unsigned int Pm) -> float {
    const bool actl = (Pm >> r) & 1u;
    float m[KDIM];
#pragma unroll
    for (int c = 0; c < KDIM; ++c) {
      const bool actc = (Pm >> c) & 1u;
      m[c] = (actl && actc) ? ata[c] : ((r == c) ? 1.f : 0.f);
    }
    float rhs = actl ? atb : 0.f;
#pragma unroll
    for (int j = 0; j < KDIM - 1; ++j) {
      if ((Pm >> j) & 1u) {
        const float inv = fast_rcp(lane_bcast(m[j], j));
        const float f = (r > j) ? m[j] * inv : 0.f;
#pragma unroll
        for (int c = j + 1; c < KDIM; ++c) m[c] = fmaf(-f, lane_bcast(m[c], j), m[c]);
        rhs = fmaf(-f, lane_bcast(rhs, j), rhs);
      }
    }
    float zz = 0.f;
#pragma unroll
    for (int j = KDIM - 1; j >= 0; --j) {
      if ((Pm >> j) & 1u) {
        const float xj = lane_bcast(rhs, j) * fast_rcp(lane_bcast(m[j], j));
        if (r == j) zz = xj;
        if (r < j) rhs = fmaf(-m[j], xj, rhs);
      }
    }
    return zz;
  };

  unsigned int P;
  float z;
  {
    const unsigned long long b0 = __ballot(atb > Z_TOL);
    const unsigned int P0 = (unsigned int)(b0 & 0xffffffffull);
    if (P0 == 0xffffffffu) {
      // shared-LU fast path: forward/back substitution only (~260 VALU)
      P = P0;
      float rhs = atb;
#pragma unroll
      for (int j = 0; j < KDIM - 1; ++j) {
        const float fj = (r > j) ? lu[j] : 0.f;
        rhs = fmaf(-fj, lane_bcast(rhs, j), rhs);
      }
      z = 0.f;
#pragma unroll
      for (int j = KDIM - 1; j >= 0; --j) {
        const float xj = lane_bcast(rhs, j) * fast_rcp(lane_bcast(lu[j], j));
        if (r == j) z = xj;
        const float uj = (r < j) ? lu[j] : 0.f;
        rhs = fmaf(-uj, xj, rhs);
      }
    } else {
      P = 0u;
      z = 0.f;
    }
  }

  // block principal pivoting with Murty least-index safeguard + hysteresis
  int ninf_best = 1000, budget = 3;
  for (int it = 0; it < 64; ++it) {
    const bool act = (P >> r) & 1u;
    const float zm = act ? z : 0.f;
    float w = atb;
#pragma unroll
    for (int c = 0; c < KDIM; ++c) w = fmaf(-ata[c], lane_bcast(zm, c), w);
    const unsigned long long bb = __ballot(act && (z <= Z_TOL));
    const unsigned long long vb = __ballot((!act) && (w > W_TOL));
    const unsigned int bad = (unsigned int)(bb & 0xffffffffull);
    const unsigned int viol = (unsigned int)(vb & 0xffffffffull);
    const unsigned int u = bad | viol;
    if (u == 0u) break;  // hysteresis-KKT satisfied (uniform)
    const int ninf = __popc(u);
    bool useblock;
    if (ninf < ninf_best) { ninf_best = ninf; budget = 3; useblock = true; }
    else if (budget > 0) { --budget; useblock = true; }
    else { useblock = false; }
    if (useblock) {
      P = (P & ~bad) | viol;
    } else {
      const int j = __ffs(u) - 1;  // Murty: least-index single flip
      P ^= (1u << j);
    }
    z = solve(P);
  }

  if (l < KDIM) S[r * NDIM + n] = ((P >> r) & 1u) ? z : 0.f;
}

extern "C" void kernel_launch(void* const* d_in, const int* in_sizes, int n_in,
                              void* d_out, int out_size, void* d_ws, size_t ws_size,
                              hipStream_t stream) {
  const float* X = (const float*)d_in[0];  // [256, 2048]
  const float* A = (const float*)d_in[1];  // [256, 32]
  float* S = (float*)d_out;                // [32, 2048]
  float* AtA = (float*)d_ws;               // 1024 floats
  float* LU = AtA + KDIM * KDIM;           // 1024 floats

  ata_kernel<<<1, 1024, 0, stream>>>(A, AtA, LU);
  nnls_kernel<<<NDIM, 64, 0, stream>>>(A, AtA, LU, X, S);
}